// Round 22
// baseline (115.458 us; speedup 1.0000x reference)
//
#include <hip/hip_runtime.h>
#include <hip/hip_bf16.h>
#include <math.h>

// Problem constants
#define BB 2
#define NN 2048
#define CC 768
#define NHEAD 12
#define HD 64
#define C3 2304
#define NSP 2  // split-K factor

typedef __attribute__((ext_vector_type(8))) _Float16 half8;
typedef __attribute__((ext_vector_type(4))) _Float16 half4;
typedef __attribute__((ext_vector_type(8))) short short8;
typedef __attribute__((ext_vector_type(4))) float f32x4;
typedef __attribute__((ext_vector_type(2))) unsigned uint2v;
#define MFMAH(a, b, c) __builtin_amdgcn_mfma_f32_16x16x32_f16(a, b, c, 0, 0, 0)
#define MFMAH16(a, b, c) __builtin_amdgcn_mfma_f32_16x16x16f16(a, b, c, 0, 0, 0)

__device__ __forceinline__ float fast_exp2(float x) {
  return __builtin_amdgcn_exp2f(x);  // v_exp_f32 (natively 2^x)
}
__device__ __forceinline__ ushort f2h(float x) {
  _Float16 h = (_Float16)x;  // v_cvt_f16_f32, RTN
  return __builtin_bit_cast(ushort, h);
}
__device__ __forceinline__ float h2f(ushort u) {
  return (float)__builtin_bit_cast(_Float16, u);  // v_cvt_f32_f16
}
__device__ __forceinline__ unsigned pk2h(float a, float b) {
  return __builtin_bit_cast(unsigned, __builtin_amdgcn_cvt_pkrtz(a, b));
}
__device__ __forceinline__ void gload_lds16(const void* gsrc, void* lds) {
  __builtin_amdgcn_global_load_lds(
      (const __attribute__((address_space(1))) unsigned int*)gsrc,
      (__attribute__((address_space(3))) unsigned int*)lds, 16, 0, 0);
}
__device__ __forceinline__ half8 ld_h8(const ushort* p) {
  return __builtin_bit_cast(half8, *reinterpret_cast<const short8*>(p));
}
__device__ __forceinline__ half4 ld_h4(const ushort* p) {
  return __builtin_bit_cast(half4, *reinterpret_cast<const uint2v*>(p));
}

// ---------------- fp32 -> f16 convert (rows) ----------------
__global__ __launch_bounds__(256) void conv_rows_kernel(const float* __restrict__ X,
                                                        ushort* __restrict__ Xf) {
  int idx = blockIdx.x * 256 + threadIdx.x;  // each converts 8 elems
  const float4 v0 = *reinterpret_cast<const float4*>(&X[(size_t)idx * 8]);
  const float4 v1 = *reinterpret_cast<const float4*>(&X[(size_t)idx * 8 + 4]);
  ushort h[8] = {f2h(v0.x), f2h(v0.y), f2h(v0.z), f2h(v0.w),
                 f2h(v1.x), f2h(v1.y), f2h(v1.z), f2h(v1.w)};
  *reinterpret_cast<uint4*>(&Xf[(size_t)idx * 8]) = *reinterpret_cast<uint4*>(h);
}

// ---------------- W [768][N] fp32 -> Wf [N][768] f16 ----------------
__global__ __launch_bounds__(256) void conv_transpose_kernel(const float* __restrict__ W,
                                                             ushort* __restrict__ Wf,
                                                             int N) {
  __shared__ float t[32][33];
  const int tx = threadIdx.x & 31, ty = threadIdx.x >> 5;  // 32 x 8
  const int n0 = blockIdx.x * 32, k0 = blockIdx.y * 32;
#pragma unroll
  for (int r = 0; r < 4; r++) {
    int kk = ty + r * 8;
    t[kk][tx] = W[(size_t)(k0 + kk) * N + n0 + tx];
  }
  __syncthreads();
#pragma unroll
  for (int r = 0; r < 4; r++) {
    int nn = ty + r * 8;
    Wf[(size_t)(n0 + nn) * CC + k0 + tx] = f2h(t[tx][nn]);
  }
}

// ---------------- f16 MFMA GEMM: C = A @ B^T, BK=64, BN=96 ----------------
// VOUT: columns >=1536 are the V projection; write them DIRECTLY transposed
// into Vt [bh][d][n] f16. Other columns -> qkvh f16 row-major.
template <int BM, bool F16OUT, bool VOUT>
__global__ __launch_bounds__(256) void gemm_f16_kernel(const ushort* __restrict__ A,
                                                       const ushort* __restrict__ B,
                                                       void* __restrict__ Cout,
                                                       ushort* __restrict__ Vt,
                                                       int Nn) {
  constexpr int WM = BM / 2;   // 64 or 32
  constexpr int MR = WM / 16;  // 4 or 2
  constexpr int NR = 3;        // 48/16
  __shared__ __align__(16) ushort Asm[BM * 64];
  __shared__ __align__(16) ushort Bsm[96 * 64];
  const int tid = threadIdx.x;
  const int lane = tid & 63, w = tid >> 6;
  const int l15 = lane & 15, lg = lane >> 4;
  const int wr = w >> 1, wc = w & 1;
  const int m0 = blockIdx.y * BM, n0 = blockIdx.x * 96;
  const int srow = lane >> 3, lc = lane & 7;
  const int scp = lc ^ (srow & 7);  // pre-swizzled logical chunk

  f32x4 acc[MR][NR];
#pragma unroll
  for (int m = 0; m < MR; m++)
#pragma unroll
    for (int n = 0; n < NR; n++) acc[m][n] = (f32x4){0.f, 0.f, 0.f, 0.f};

  for (int k0 = 0; k0 < 768; k0 += 64) {
#pragma unroll
    for (int it = 0; it < BM / 32; it++) {
      int r0 = it * 32 + w * 8;
      int row = r0 + srow;
      gload_lds16(A + (size_t)(m0 + row) * CC + k0 + scp * 8, &Asm[r0 * 64]);
    }
#pragma unroll
    for (int it = 0; it < 3; it++) {
      int r0 = it * 32 + w * 8;
      int row = r0 + srow;
      gload_lds16(B + (size_t)(n0 + row) * CC + k0 + scp * 8, &Bsm[r0 * 64]);
    }
    __syncthreads();

    half8 ah[MR][2], bh[NR][2];
#pragma unroll
    for (int m = 0; m < MR; m++) {
      int row = wr * WM + m * 16 + l15;
#pragma unroll
      for (int s = 0; s < 2; s++)
        ah[m][s] = ld_h8(&Asm[row * 64 + ((s * 4 + lg) ^ (row & 7)) * 8]);
    }
#pragma unroll
    for (int n = 0; n < NR; n++) {
      int col = wc * 48 + n * 16 + l15;
#pragma unroll
      for (int s = 0; s < 2; s++)
        bh[n][s] = ld_h8(&Bsm[col * 64 + ((s * 4 + lg) ^ (col & 7)) * 8]);
    }
#pragma unroll
    for (int s = 0; s < 2; s++)
#pragma unroll
      for (int m = 0; m < MR; m++)
#pragma unroll
        for (int n = 0; n < NR; n++)
          acc[m][n] = MFMAH(ah[m][s], bh[n][s], acc[m][n]);
    __syncthreads();
  }

#pragma unroll
  for (int m = 0; m < MR; m++) {
    const int rbase = m0 + wr * WM + m * 16 + lg * 4;  // 4 consecutive tokens
#pragma unroll
    for (int n = 0; n < NR; n++) {
      int col = n0 + wc * 48 + n * 16 + l15;
      if (VOUT && col >= 1536) {
        const int vcol = col - 1536;
        const int b = rbase >> 11, ntok = rbase & 2047;
        const int bh_ = b * NHEAD + (vcol >> 6), d = vcol & 63;
        uint2v pw = {pk2h(acc[m][n][0], acc[m][n][1]),
                     pk2h(acc[m][n][2], acc[m][n][3])};
        *reinterpret_cast<uint2v*>(Vt + ((size_t)bh_ * HD + d) * NN + ntok) = pw;
      } else {
#pragma unroll
        for (int j = 0; j < 4; j++) {
          if constexpr (F16OUT) {
            ((ushort*)Cout)[(size_t)(rbase + j) * Nn + col] = f2h(acc[m][n][j]);
          } else {
            ((float*)Cout)[(size_t)(rbase + j) * Nn + col] = acc[m][n][j];
          }
        }
      }
    }
  }
}

// ---------------- RoPE (Q/K), 8-wide vectorized, pair-symmetric ----------------
// Thread owns 8 consecutive dims in the FIRST half of a rotation segment and
// produces both halves (16 q + 16 k outputs), all uint4/float4 accesses.
// 48 groups/token; grid = 4096*48/256 = 768 blocks.
__global__ __launch_bounds__(256) void rope_f16_kernel(
    const ushort* __restrict__ qkvh, const float* __restrict__ cos_t,
    const float* __restrict__ sin_t, const float* __restrict__ cos_h,
    const float* __restrict__ sin_h, const float* __restrict__ cos_w,
    const float* __restrict__ sin_w, const int* __restrict__ t_idx,
    const int* __restrict__ h_idx, const int* __restrict__ w_idx,
    ushort* __restrict__ Qf, ushort* __restrict__ Kf) {
  const int gid = blockIdx.x * 256 + threadIdx.x;  // 0..196607
  const int tok = gid / 48, grp = gid - tok * 48;
  const int b = tok >> 11, n = tok & 2047;
  const float QSC = 0.125f * 1.44269504088896f;

  int j0, off;
  const float *cT, *sT;  // offset so cT[j] indexes by ABSOLUTE j
  if (grp < 12) {
    j0 = grp * 8;
    off = 96;
    const int ti = t_idx[n];
    cT = cos_t + ti * 192;
    sT = sin_t + ti * 192;
  } else if (grp < 30) {
    j0 = 192 + (grp - 12) * 8;
    off = 144;
    const int hi = h_idx[n];
    cT = cos_h + hi * 288 - 192;
    sT = sin_h + hi * 288 - 192;
  } else {
    j0 = 480 + (grp - 30) * 8;
    off = 144;
    const int wi = w_idx[n];
    cT = cos_w + wi * 288 - 480;
    sT = sin_w + wi * 288 - 480;
  }

  const ushort* base = qkvh + (size_t)tok * C3;
  ushort qa[8], qb[8], ka[8], kb[8];
  *reinterpret_cast<uint4*>(qa) = *reinterpret_cast<const uint4*>(base + j0);
  *reinterpret_cast<uint4*>(qb) = *reinterpret_cast<const uint4*>(base + j0 + off);
  *reinterpret_cast<uint4*>(ka) = *reinterpret_cast<const uint4*>(base + 768 + j0);
  *reinterpret_cast<uint4*>(kb) = *reinterpret_cast<const uint4*>(base + 768 + j0 + off);
  float ca[8], sa[8], cb[8], sb[8];
  *reinterpret_cast<float4*>(ca) = *reinterpret_cast<const float4*>(cT + j0);
  *reinterpret_cast<float4*>(ca + 4) = *reinterpret_cast<const float4*>(cT + j0 + 4);
  *reinterpret_cast<float4*>(sa) = *reinterpret_cast<const float4*>(sT + j0);
  *reinterpret_cast<float4*>(sa + 4) = *reinterpret_cast<const float4*>(sT + j0 + 4);
  *reinterpret_cast<float4*>(cb) = *reinterpret_cast<const float4*>(cT + j0 + off);
  *reinterpret_cast<float4*>(cb + 4) = *reinterpret_cast<const float4*>(cT + j0 + off + 4);
  *reinterpret_cast<float4*>(sb) = *reinterpret_cast<const float4*>(sT + j0 + off);
  *reinterpret_cast<float4*>(sb + 4) = *reinterpret_cast<const float4*>(sT + j0 + off + 4);

  ushort qoA[8], qoB[8], koA[8], koB[8];
#pragma unroll
  for (int i = 0; i < 8; i++) {
    float qA = h2f(qa[i]), qB = h2f(qb[i]);
    float kA = h2f(ka[i]), kB = h2f(kb[i]);
    qoA[i] = f2h(fmaf(qA, ca[i], -qB * sa[i]) * QSC);  // first half: x*c - x2*s
    qoB[i] = f2h(fmaf(qB, cb[i], qA * sb[i]) * QSC);   // second half: x*c + x1*s
    koA[i] = f2h(fmaf(kA, ca[i], -kB * sa[i]));
    koB[i] = f2h(fmaf(kB, cb[i], kA * sb[i]));
  }

  // write: j -> (h = j>>6, d = j&63); 8-aligned groups stay within one head
  const size_t tb = (size_t)(b * NHEAD) * NN * HD + (size_t)n * HD;
  {
    const size_t oA = tb + (size_t)(j0 >> 6) * NN * HD + (j0 & 63);
    const size_t oB = tb + (size_t)((j0 + off) >> 6) * NN * HD + ((j0 + off) & 63);
    *reinterpret_cast<uint4*>(Qf + oA) = *reinterpret_cast<uint4*>(qoA);
    *reinterpret_cast<uint4*>(Qf + oB) = *reinterpret_cast<uint4*>(qoB);
    *reinterpret_cast<uint4*>(Kf + oA) = *reinterpret_cast<uint4*>(koA);
    *reinterpret_cast<uint4*>(Kf + oB) = *reinterpret_cast<uint4*>(koB);
  }
}

// ---------------- f16 MFMA flash attention, QBLK=64, split-K=2, 6 blocks/CU ----
// Exact R19 config: 24KB LDS (K single + V double), PV via 16x16x16, 40 VGPR.
__global__ __launch_bounds__(256, 6) void attn_mfma_kernel(
    const ushort* __restrict__ Qf, const ushort* __restrict__ Kf,
    const ushort* __restrict__ Vt, float* __restrict__ PartO,
    float* __restrict__ Partml) {
  __shared__ __align__(16) ushort smemK[4096];     // 8KB
  __shared__ __align__(16) ushort smemV[2][4096];  // 16KB
  const int tid = threadIdx.x;
  const int lane = tid & 63, w = tid >> 6;
  const int l15 = lane & 15, lg = lane >> 4;
  const int qt = blockIdx.x;  // 0..31 (64 q-rows each)
  const int bh = blockIdx.y;  // 0..23
  const int sp = blockIdx.z;  // 0..1 (k-range split)
  const size_t kbase = (size_t)bh * NN * HD;  // Qf/Kf token-major
  const size_t vbase = (size_t)bh * HD * NN;  // Vt d-major

  half8 qf[2];
  {
    const int r = qt * 64 + w * 16 + l15;
#pragma unroll
    for (int s = 0; s < 2; s++)
      qf[s] = ld_h8(Qf + kbase + (size_t)r * HD + s * 32 + lg * 8);
  }

  const int srow = lane >> 3;        // staging row-within-group 0..7
  const int sc = (lane & 7) ^ srow;  // pre-swizzled logical chunk

#define STAGE_K(kt_)                                                           \
  {                                                                            \
    _Pragma("unroll") for (int it = 0; it < 2; it++) {                         \
      int r0 = it * 32 + w * 8;                                                \
      int r = r0 + srow;                                                       \
      gload_lds16(Kf + kbase + (size_t)((kt_)*64 + r) * 64 + sc * 8,           \
                  &smemK[r0 * 64]);                                            \
    }                                                                          \
  }
#define STAGE_V(kt_, vb_)                                                      \
  {                                                                            \
    _Pragma("unroll") for (int it = 0; it < 2; it++) {                         \
      int r0 = it * 32 + w * 8;                                                \
      int r = r0 + srow;                                                       \
      gload_lds16(Vt + vbase + (size_t)r * NN + (kt_)*64 + sc * 8,             \
                  &smemV[vb_][r0 * 64]);                                       \
    }                                                                          \
  }

  f32x4 o_acc[4];
#pragma unroll
  for (int g = 0; g < 4; g++) o_acc[g] = (f32x4){0.f, 0.f, 0.f, 0.f};
  float m_run = -INFINITY, l_run = 0.f;  // per-lane partials

  const int rmask7 = l15 & 7;
  const int kt0 = sp * (32 / NSP), ktend = kt0 + (32 / NSP);

  STAGE_V(kt0, 0);
  STAGE_K(kt0);

  for (int kt = kt0; kt < ktend; kt++) {
    const int cur = (kt - kt0) & 1;
    __syncthreads();  // barA: K(kt), V(kt,cur) visible; V[cur^1] free of reads
    if (kt + 1 < ktend) STAGE_V(kt + 1, cur ^ 1);  // lands under this tile

    // ---- S^T = K Q^T (f16, 16x16x32) ----
    f32x4 s_acc[4];
#pragma unroll
    for (int g = 0; g < 4; g++) s_acc[g] = (f32x4){0.f, 0.f, 0.f, 0.f};
    __builtin_amdgcn_s_setprio(1);
#pragma unroll
    for (int g = 0; g < 4; g++) {
      const int r = g * 16 + l15;
#pragma unroll
      for (int s = 0; s < 2; s++) {
        half8 ka = ld_h8(&smemK[r * 64 + ((s * 4 + lg) ^ rmask7) * 8]);
        s_acc[g] = MFMAH(ka, qf[s], s_acc[g]);
      }
    }
    __builtin_amdgcn_s_setprio(0);

    __syncthreads();                      // barB: all waves done reading K(kt)
    if (kt + 1 < ktend) STAGE_K(kt + 1);  // lands under softmax+PV

    // ---- softmax (exp2 domain), defer-max THR=8 ----
    float m0a = fmaxf(fmaxf(s_acc[0][0], s_acc[0][1]), fmaxf(s_acc[0][2], s_acc[0][3]));
    float m1a = fmaxf(fmaxf(s_acc[1][0], s_acc[1][1]), fmaxf(s_acc[1][2], s_acc[1][3]));
    float m2a = fmaxf(fmaxf(s_acc[2][0], s_acc[2][1]), fmaxf(s_acc[2][2], s_acc[2][3]));
    float m3a = fmaxf(fmaxf(s_acc[3][0], s_acc[3][1]), fmaxf(s_acc[3][2], s_acc[3][3]));
    float pm = fmaxf(fmaxf(m0a, m1a), fmaxf(m2a, m3a));
    pm = fmaxf(pm, __shfl_xor(pm, 16, 64));
    pm = fmaxf(pm, __shfl_xor(pm, 32, 64));
    if (!__all(pm - m_run <= 8.0f)) {
      const float mn = fmaxf(m_run, pm);
      const float corr = fast_exp2(m_run - mn);
      m_run = mn;
      l_run *= corr;
#pragma unroll
      for (int g = 0; g < 4; g++)
#pragma unroll
        for (int j = 0; j < 4; j++) o_acc[g][j] *= corr;
    }
    float p[4][4];
#pragma unroll
    for (int g = 0; g < 4; g++)
#pragma unroll
      for (int j = 0; j < 4; j++) {
        p[g][j] = fast_exp2(s_acc[g][j] - m_run);
        l_run += p[g][j];
      }

    // ---- PV via 16x16x16: B-frag = p[kb][0..3] directly (no butterfly) ----
    __builtin_amdgcn_s_setprio(1);
#pragma unroll
    for (int kb = 0; kb < 4; kb++) {
      uint2v pw = {pk2h(p[kb][0], p[kb][1]), pk2h(p[kb][2], p[kb][3])};
      half4 pbh = __builtin_bit_cast(half4, pw);
      const int c = kb * 2 + (lg >> 1);
      const int off = ((c ^ rmask7) * 8 + (lg & 1) * 4);
#pragma unroll
      for (int g = 0; g < 4; g++) {
        half4 va = ld_h4(&smemV[cur][(g * 16 + l15) * 64 + off]);
        o_acc[g] = MFMAH16(va, pbh, o_acc[g]);
      }
    }
    __builtin_amdgcn_s_setprio(0);
  }

  // ---- epilogue: reduce l across the 4 q-column lanes, write partials ----
  l_run += __shfl_xor(l_run, 16, 64);
  l_run += __shfl_xor(l_run, 32, 64);
  const int q = qt * 64 + w * 16 + l15;
  const size_t pidx = ((size_t)(sp * 24 + bh) * NN + q);
#pragma unroll
  for (int g = 0; g < 4; g++) {
    *reinterpret_cast<float4*>(&PartO[pidx * 64 + g * 16 + lg * 4]) =
        make_float4(o_acc[g][0], o_acc[g][1], o_acc[g][2], o_acc[g][3]);
  }
  if (lg == 0) {
    Partml[pidx * 2] = m_run;
    Partml[pidx * 2 + 1] = l_run;
  }
#undef STAGE_K
#undef STAGE_V
}

// ---------------- split-K combine: merge NSP partials -> attnf f16 ----------------
__global__ __launch_bounds__(256) void attn_combine_kernel(
    const float* __restrict__ PartO, const float* __restrict__ Partml,
    ushort* __restrict__ Attnf) {
  const int qt = blockIdx.x;  // 0..31
  const int bh = blockIdx.y;  // 0..23
  const int b = bh / NHEAD, h = bh % NHEAD;
  const int tid = threadIdx.x;
  const int q = qt * 64 + (tid >> 2);
  const int d0 = (tid & 3) * 16;

  size_t idx[NSP];
  float mv[NSP], lv[NSP];
  float m = -INFINITY;
#pragma unroll
  for (int s = 0; s < NSP; s++) {
    idx[s] = ((size_t)(s * 24 + bh) * NN + q);
    mv[s] = Partml[idx[s] * 2];
    lv[s] = Partml[idx[s] * 2 + 1];
    m = fmaxf(m, mv[s]);
  }
  float wsum = 0.f, wgt[NSP];
#pragma unroll
  for (int s = 0; s < NSP; s++) {
    wgt[s] = fast_exp2(mv[s] - m);
    wsum += lv[s] * wgt[s];
  }
  const float inv = 1.0f / wsum;

  ushort hv[16];
#pragma unroll
  for (int d = 0; d < 16; d += 4) {
    float acc[4] = {0.f, 0.f, 0.f, 0.f};
#pragma unroll
    for (int s = 0; s < NSP; s++) {
      float4 a = *reinterpret_cast<const float4*>(&PartO[idx[s] * 64 + d0 + d]);
      acc[0] = fmaf(a.x, wgt[s], acc[0]);
      acc[1] = fmaf(a.y, wgt[s], acc[1]);
      acc[2] = fmaf(a.z, wgt[s], acc[2]);
      acc[3] = fmaf(a.w, wgt[s], acc[3]);
    }
#pragma unroll
    for (int i = 0; i < 4; i++) hv[d + i] = f2h(acc[i] * inv);
  }
  ushort* dst = Attnf + (size_t)(b * NN + q) * CC + h * 64 + d0;
  *reinterpret_cast<uint4*>(dst) = *reinterpret_cast<uint4*>(hv);
  *reinterpret_cast<uint4*>(dst + 8) = *reinterpret_cast<uint4*>(hv + 8);
}

// ---------------- launch ----------------
extern "C" void kernel_launch(void* const* d_in, const int* in_sizes, int n_in,
                              void* d_out, int out_size, void* d_ws, size_t ws_size,
                              hipStream_t stream) {
  const float* x = (const float*)d_in[0];
  const float* Wqkv = (const float*)d_in[1];
  const float* Wout = (const float*)d_in[2];
  const float* cos_t = (const float*)d_in[3];
  const float* sin_t = (const float*)d_in[4];
  const float* cos_h = (const float*)d_in[5];
  const float* sin_h = (const float*)d_in[6];
  const float* cos_w = (const float*)d_in[7];
  const float* sin_w = (const float*)d_in[8];
  const int* t_idx = (const int*)d_in[9];
  const int* h_idx = (const int*)d_in[10];
  const int* w_idx = (const int*)d_in[11];
  float* out = (float*)d_out;

  // region0: aliased by qkvh (f16 4096x2304, live gemm->rope) and
  // PartO (NSP*24*2048*64 f32 = 6.29M floats, live attn->combine). Disjoint.
  const size_t R0 = (size_t)4096 * 2304;  // floats
  float* ws = (float*)d_ws;
  ushort* qkvh = (ushort*)ws;
  float* PartO = ws;
  ushort* us = (ushort*)(ws + R0);
  const size_t HS = (size_t)24 * 2048 * 64;  // 3.14M
  ushort* Qf = us;
  ushort* Kf = Qf + HS;
  ushort* Vt = Kf + HS;
  ushort* xf = Vt + HS;                     // 4096*768
  ushort* wqf = xf + (size_t)4096 * 768;    // 2304*768
  ushort* wof = wqf + (size_t)2304 * 768;   // 768*768
  ushort* attnf = wof + (size_t)768 * 768;  // 4096*768
  float* Partml = (float*)(attnf + (size_t)4096 * 768);  // NSP*24*2048*2 fp32

  // input conversions (f16)
  conv_rows_kernel<<<dim3(4096 * 768 / 8 / 256), 256, 0, stream>>>(x, xf);
  conv_transpose_kernel<<<dim3(C3 / 32, CC / 32), 256, 0, stream>>>(Wqkv, wqf, C3);
  conv_transpose_kernel<<<dim3(CC / 32, CC / 32), 256, 0, stream>>>(Wout, wof, CC);
  // qkv = x @ Wqkv; q,k -> qkvh f16 row-major, v -> Vt transposed directly
  gemm_f16_kernel<128, true, true><<<dim3(C3 / 96, 4096 / 128), 256, 0, stream>>>(
      xf, wqf, qkvh, Vt, C3);
  // RoPE Q/K (vectorized 8-wide, 768 blocks)
  rope_f16_kernel<<<dim3(BB * NN * 48 / 256), 256, 0, stream>>>(
      qkvh, cos_t, sin_t, cos_h, sin_h, cos_w, sin_w, t_idx, h_idx, w_idx, Qf, Kf);
  // flash attention (f16 MFMA, QBLK=64, split-K=2 -> 1536 blocks = 6/CU)
  attn_mfma_kernel<<<dim3(NN / 64, BB * NHEAD, NSP), 256, 0, stream>>>(Qf, Kf, Vt,
                                                                       PartO, Partml);
  // combine partials -> f16 attnf
  attn_combine_kernel<<<dim3(NN / 64, BB * NHEAD), 256, 0, stream>>>(PartO, Partml,
                                                                     attnf);
  // out = attn @ Wout  (f16 MFMA, fp32 output)
  gemm_f16_kernel<64, false, false><<<dim3(CC / 96, 4096 / 64), 256, 0, stream>>>(
      attnf, wof, out, nullptr, CC);
}

// Round 23
// 109.915 us; speedup vs baseline: 1.0504x; 1.0504x over previous
//
#include <hip/hip_runtime.h>
#include <hip/hip_bf16.h>
#include <math.h>

// Problem constants
#define BB 2
#define NN 2048
#define CC 768
#define NHEAD 12
#define HD 64
#define C3 2304
#define NSP 2  // split-K factor

typedef __attribute__((ext_vector_type(8))) _Float16 half8;
typedef __attribute__((ext_vector_type(4))) _Float16 half4;
typedef __attribute__((ext_vector_type(8))) short short8;
typedef __attribute__((ext_vector_type(4))) float f32x4;
typedef __attribute__((ext_vector_type(2))) unsigned uint2v;
#define MFMAH(a, b, c) __builtin_amdgcn_mfma_f32_16x16x32_f16(a, b, c, 0, 0, 0)
#define MFMAH16(a, b, c) __builtin_amdgcn_mfma_f32_16x16x16f16(a, b, c, 0, 0, 0)

__device__ __forceinline__ float fast_exp2(float x) {
  return __builtin_amdgcn_exp2f(x);  // v_exp_f32 (natively 2^x)
}
__device__ __forceinline__ ushort f2h(float x) {
  _Float16 h = (_Float16)x;  // v_cvt_f16_f32, RTN
  return __builtin_bit_cast(ushort, h);
}
__device__ __forceinline__ float h2f(ushort u) {
  return (float)__builtin_bit_cast(_Float16, u);  // v_cvt_f32_f16
}
__device__ __forceinline__ unsigned pk2h(float a, float b) {
  return __builtin_bit_cast(unsigned, __builtin_amdgcn_cvt_pkrtz(a, b));
}
__device__ __forceinline__ void gload_lds16(const void* gsrc, void* lds) {
  __builtin_amdgcn_global_load_lds(
      (const __attribute__((address_space(1))) unsigned int*)gsrc,
      (__attribute__((address_space(3))) unsigned int*)lds, 16, 0, 0);
}
__device__ __forceinline__ half8 ld_h8(const ushort* p) {
  return __builtin_bit_cast(half8, *reinterpret_cast<const short8*>(p));
}
__device__ __forceinline__ half4 ld_h4(const ushort* p) {
  return __builtin_bit_cast(half4, *reinterpret_cast<const uint2v*>(p));
}

// ---------------- merged conversions: x rows + Wqkv^T + Wout^T, one dispatch ----
// blocks [0,1536): x fp32 -> xf f16 (8 elems/thread)
// blocks [1536,3264): Wqkv [768][2304] -> wqf [2304][768] f16
// blocks [3264,3840): Wout [768][768] -> wof [768][768] f16
__global__ __launch_bounds__(256) void conv_all_kernel(
    const float* __restrict__ X, ushort* __restrict__ Xf,
    const float* __restrict__ Wqkv, ushort* __restrict__ Wqf,
    const float* __restrict__ Wout, ushort* __restrict__ Wof) {
  __shared__ float t[32][33];
  const int bid = blockIdx.x;
  if (bid < 1536) {
    int idx = bid * 256 + threadIdx.x;
    const float4 v0 = *reinterpret_cast<const float4*>(&X[(size_t)idx * 8]);
    const float4 v1 = *reinterpret_cast<const float4*>(&X[(size_t)idx * 8 + 4]);
    ushort h[8] = {f2h(v0.x), f2h(v0.y), f2h(v0.z), f2h(v0.w),
                   f2h(v1.x), f2h(v1.y), f2h(v1.z), f2h(v1.w)};
    *reinterpret_cast<uint4*>(&Xf[(size_t)idx * 8]) = *reinterpret_cast<uint4*>(h);
    return;
  }
  const float* W;
  ushort* Wf;
  int N, n0, k0;
  if (bid < 3264) {
    W = Wqkv;
    Wf = Wqf;
    N = C3;
    const int b2 = bid - 1536;  // 72 x-tiles, 24 y-tiles
    n0 = (b2 % 72) * 32;
    k0 = (b2 / 72) * 32;
  } else {
    W = Wout;
    Wf = Wof;
    N = CC;
    const int b3 = bid - 3264;  // 24 x-tiles, 24 y-tiles
    n0 = (b3 % 24) * 32;
    k0 = (b3 / 24) * 32;
  }
  const int tx = threadIdx.x & 31, ty = threadIdx.x >> 5;  // 32 x 8
#pragma unroll
  for (int r = 0; r < 4; r++) {
    int kk = ty + r * 8;
    t[kk][tx] = W[(size_t)(k0 + kk) * N + n0 + tx];
  }
  __syncthreads();
#pragma unroll
  for (int r = 0; r < 4; r++) {
    int nn = ty + r * 8;
    Wf[(size_t)(n0 + nn) * CC + k0 + tx] = f2h(t[tx][nn]);
  }
}

// ---------------- f16 MFMA GEMM: C = A @ B^T, BK=64, BN=96 ----------------
// VOUT: columns >=1536 are the V projection; write them DIRECTLY transposed
// into Vt [bh][d][n] f16. Other columns -> qkvh f16 row-major.
template <int BM, bool F16OUT, bool VOUT>
__global__ __launch_bounds__(256) void gemm_f16_kernel(const ushort* __restrict__ A,
                                                       const ushort* __restrict__ B,
                                                       void* __restrict__ Cout,
                                                       ushort* __restrict__ Vt,
                                                       int Nn) {
  constexpr int WM = BM / 2;   // 64 or 32
  constexpr int MR = WM / 16;  // 4 or 2
  constexpr int NR = 3;        // 48/16
  __shared__ __align__(16) ushort Asm[BM * 64];
  __shared__ __align__(16) ushort Bsm[96 * 64];
  const int tid = threadIdx.x;
  const int lane = tid & 63, w = tid >> 6;
  const int l15 = lane & 15, lg = lane >> 4;
  const int wr = w >> 1, wc = w & 1;
  const int m0 = blockIdx.y * BM, n0 = blockIdx.x * 96;
  const int srow = lane >> 3, lc = lane & 7;
  const int scp = lc ^ (srow & 7);  // pre-swizzled logical chunk

  f32x4 acc[MR][NR];
#pragma unroll
  for (int m = 0; m < MR; m++)
#pragma unroll
    for (int n = 0; n < NR; n++) acc[m][n] = (f32x4){0.f, 0.f, 0.f, 0.f};

  for (int k0 = 0; k0 < 768; k0 += 64) {
#pragma unroll
    for (int it = 0; it < BM / 32; it++) {
      int r0 = it * 32 + w * 8;
      int row = r0 + srow;
      gload_lds16(A + (size_t)(m0 + row) * CC + k0 + scp * 8, &Asm[r0 * 64]);
    }
#pragma unroll
    for (int it = 0; it < 3; it++) {
      int r0 = it * 32 + w * 8;
      int row = r0 + srow;
      gload_lds16(B + (size_t)(n0 + row) * CC + k0 + scp * 8, &Bsm[r0 * 64]);
    }
    __syncthreads();

    half8 ah[MR][2], bh[NR][2];
#pragma unroll
    for (int m = 0; m < MR; m++) {
      int row = wr * WM + m * 16 + l15;
#pragma unroll
      for (int s = 0; s < 2; s++)
        ah[m][s] = ld_h8(&Asm[row * 64 + ((s * 4 + lg) ^ (row & 7)) * 8]);
    }
#pragma unroll
    for (int n = 0; n < NR; n++) {
      int col = wc * 48 + n * 16 + l15;
#pragma unroll
      for (int s = 0; s < 2; s++)
        bh[n][s] = ld_h8(&Bsm[col * 64 + ((s * 4 + lg) ^ (col & 7)) * 8]);
    }
#pragma unroll
    for (int s = 0; s < 2; s++)
#pragma unroll
      for (int m = 0; m < MR; m++)
#pragma unroll
        for (int n = 0; n < NR; n++)
          acc[m][n] = MFMAH(ah[m][s], bh[n][s], acc[m][n]);
    __syncthreads();
  }

#pragma unroll
  for (int m = 0; m < MR; m++) {
    const int rbase = m0 + wr * WM + m * 16 + lg * 4;  // 4 consecutive tokens
#pragma unroll
    for (int n = 0; n < NR; n++) {
      int col = n0 + wc * 48 + n * 16 + l15;
      if (VOUT && col >= 1536) {
        const int vcol = col - 1536;
        const int b = rbase >> 11, ntok = rbase & 2047;
        const int bh_ = b * NHEAD + (vcol >> 6), d = vcol & 63;
        uint2v pw = {pk2h(acc[m][n][0], acc[m][n][1]),
                     pk2h(acc[m][n][2], acc[m][n][3])};
        *reinterpret_cast<uint2v*>(Vt + ((size_t)bh_ * HD + d) * NN + ntok) = pw;
      } else {
#pragma unroll
        for (int j = 0; j < 4; j++) {
          if constexpr (F16OUT) {
            ((ushort*)Cout)[(size_t)(rbase + j) * Nn + col] = f2h(acc[m][n][j]);
          } else {
            ((float*)Cout)[(size_t)(rbase + j) * Nn + col] = acc[m][n][j];
          }
        }
      }
    }
  }
}

// ---------------- RoPE (Q/K), 8-wide vectorized, pair-symmetric ----------------
__global__ __launch_bounds__(256) void rope_f16_kernel(
    const ushort* __restrict__ qkvh, const float* __restrict__ cos_t,
    const float* __restrict__ sin_t, const float* __restrict__ cos_h,
    const float* __restrict__ sin_h, const float* __restrict__ cos_w,
    const float* __restrict__ sin_w, const int* __restrict__ t_idx,
    const int* __restrict__ h_idx, const int* __restrict__ w_idx,
    ushort* __restrict__ Qf, ushort* __restrict__ Kf) {
  const int gid = blockIdx.x * 256 + threadIdx.x;  // 0..196607
  const int tok = gid / 48, grp = gid - tok * 48;
  const int b = tok >> 11, n = tok & 2047;
  const float QSC = 0.125f * 1.44269504088896f;

  int j0, off;
  const float *cT, *sT;  // offset so cT[j] indexes by ABSOLUTE j
  if (grp < 12) {
    j0 = grp * 8;
    off = 96;
    const int ti = t_idx[n];
    cT = cos_t + ti * 192;
    sT = sin_t + ti * 192;
  } else if (grp < 30) {
    j0 = 192 + (grp - 12) * 8;
    off = 144;
    const int hi = h_idx[n];
    cT = cos_h + hi * 288 - 192;
    sT = sin_h + hi * 288 - 192;
  } else {
    j0 = 480 + (grp - 30) * 8;
    off = 144;
    const int wi = w_idx[n];
    cT = cos_w + wi * 288 - 480;
    sT = sin_w + wi * 288 - 480;
  }

  const ushort* base = qkvh + (size_t)tok * C3;
  ushort qa[8], qb[8], ka[8], kb[8];
  *reinterpret_cast<uint4*>(qa) = *reinterpret_cast<const uint4*>(base + j0);
  *reinterpret_cast<uint4*>(qb) = *reinterpret_cast<const uint4*>(base + j0 + off);
  *reinterpret_cast<uint4*>(ka) = *reinterpret_cast<const uint4*>(base + 768 + j0);
  *reinterpret_cast<uint4*>(kb) = *reinterpret_cast<const uint4*>(base + 768 + j0 + off);
  float ca[8], sa[8], cb[8], sb[8];
  *reinterpret_cast<float4*>(ca) = *reinterpret_cast<const float4*>(cT + j0);
  *reinterpret_cast<float4*>(ca + 4) = *reinterpret_cast<const float4*>(cT + j0 + 4);
  *reinterpret_cast<float4*>(sa) = *reinterpret_cast<const float4*>(sT + j0);
  *reinterpret_cast<float4*>(sa + 4) = *reinterpret_cast<const float4*>(sT + j0 + 4);
  *reinterpret_cast<float4*>(cb) = *reinterpret_cast<const float4*>(cT + j0 + off);
  *reinterpret_cast<float4*>(cb + 4) = *reinterpret_cast<const float4*>(cT + j0 + off + 4);
  *reinterpret_cast<float4*>(sb) = *reinterpret_cast<const float4*>(sT + j0 + off);
  *reinterpret_cast<float4*>(sb + 4) = *reinterpret_cast<const float4*>(sT + j0 + off + 4);

  ushort qoA[8], qoB[8], koA[8], koB[8];
#pragma unroll
  for (int i = 0; i < 8; i++) {
    float qA = h2f(qa[i]), qB = h2f(qb[i]);
    float kA = h2f(ka[i]), kB = h2f(kb[i]);
    qoA[i] = f2h(fmaf(qA, ca[i], -qB * sa[i]) * QSC);  // first half: x*c - x2*s
    qoB[i] = f2h(fmaf(qB, cb[i], qA * sb[i]) * QSC);   // second half: x*c + x1*s
    koA[i] = f2h(fmaf(kA, ca[i], -kB * sa[i]));
    koB[i] = f2h(fmaf(kB, cb[i], kA * sb[i]));
  }

  const size_t tb = (size_t)(b * NHEAD) * NN * HD + (size_t)n * HD;
  {
    const size_t oA = tb + (size_t)(j0 >> 6) * NN * HD + (j0 & 63);
    const size_t oB = tb + (size_t)((j0 + off) >> 6) * NN * HD + ((j0 + off) & 63);
    *reinterpret_cast<uint4*>(Qf + oA) = *reinterpret_cast<uint4*>(qoA);
    *reinterpret_cast<uint4*>(Qf + oB) = *reinterpret_cast<uint4*>(qoB);
    *reinterpret_cast<uint4*>(Kf + oA) = *reinterpret_cast<uint4*>(koA);
    *reinterpret_cast<uint4*>(Kf + oB) = *reinterpret_cast<uint4*>(koB);
  }
}

// ---------------- f16 MFMA flash attention, QBLK=64, split-K=2, 6 blocks/CU ----
__global__ __launch_bounds__(256, 6) void attn_mfma_kernel(
    const ushort* __restrict__ Qf, const ushort* __restrict__ Kf,
    const ushort* __restrict__ Vt, float* __restrict__ PartO,
    float* __restrict__ Partml) {
  __shared__ __align__(16) ushort smemK[4096];     // 8KB
  __shared__ __align__(16) ushort smemV[2][4096];  // 16KB
  const int tid = threadIdx.x;
  const int lane = tid & 63, w = tid >> 6;
  const int l15 = lane & 15, lg = lane >> 4;
  const int qt = blockIdx.x;  // 0..31 (64 q-rows each)
  const int bh = blockIdx.y;  // 0..23
  const int sp = blockIdx.z;  // 0..1 (k-range split)
  const size_t kbase = (size_t)bh * NN * HD;  // Qf/Kf token-major
  const size_t vbase = (size_t)bh * HD * NN;  // Vt d-major

  half8 qf[2];
  {
    const int r = qt * 64 + w * 16 + l15;
#pragma unroll
    for (int s = 0; s < 2; s++)
      qf[s] = ld_h8(Qf + kbase + (size_t)r * HD + s * 32 + lg * 8);
  }

  const int srow = lane >> 3;        // staging row-within-group 0..7
  const int sc = (lane & 7) ^ srow;  // pre-swizzled logical chunk

#define STAGE_K(kt_)                                                           \
  {                                                                            \
    _Pragma("unroll") for (int it = 0; it < 2; it++) {                         \
      int r0 = it * 32 + w * 8;                                                \
      int r = r0 + srow;                                                       \
      gload_lds16(Kf + kbase + (size_t)((kt_)*64 + r) * 64 + sc * 8,           \
                  &smemK[r0 * 64]);                                            \
    }                                                                          \
  }
#define STAGE_V(kt_, vb_)                                                      \
  {                                                                            \
    _Pragma("unroll") for (int it = 0; it < 2; it++) {                         \
      int r0 = it * 32 + w * 8;                                                \
      int r = r0 + srow;                                                       \
      gload_lds16(Vt + vbase + (size_t)r * NN + (kt_)*64 + sc * 8,             \
                  &smemV[vb_][r0 * 64]);                                       \
    }                                                                          \
  }

  f32x4 o_acc[4];
#pragma unroll
  for (int g = 0; g < 4; g++) o_acc[g] = (f32x4){0.f, 0.f, 0.f, 0.f};
  float m_run = -INFINITY, l_run = 0.f;  // per-lane partials

  const int rmask7 = l15 & 7;
  const int kt0 = sp * (32 / NSP), ktend = kt0 + (32 / NSP);

  STAGE_V(kt0, 0);
  STAGE_K(kt0);

  for (int kt = kt0; kt < ktend; kt++) {
    const int cur = (kt - kt0) & 1;
    __syncthreads();  // barA: K(kt), V(kt,cur) visible; V[cur^1] free of reads
    if (kt + 1 < ktend) STAGE_V(kt + 1, cur ^ 1);  // lands under this tile

    // ---- S^T = K Q^T (f16, 16x16x32) ----
    f32x4 s_acc[4];
#pragma unroll
    for (int g = 0; g < 4; g++) s_acc[g] = (f32x4){0.f, 0.f, 0.f, 0.f};
    __builtin_amdgcn_s_setprio(1);
#pragma unroll
    for (int g = 0; g < 4; g++) {
      const int r = g * 16 + l15;
#pragma unroll
      for (int s = 0; s < 2; s++) {
        half8 ka = ld_h8(&smemK[r * 64 + ((s * 4 + lg) ^ rmask7) * 8]);
        s_acc[g] = MFMAH(ka, qf[s], s_acc[g]);
      }
    }
    __builtin_amdgcn_s_setprio(0);

    __syncthreads();                      // barB: all waves done reading K(kt)
    if (kt + 1 < ktend) STAGE_K(kt + 1);  // lands under softmax+PV

    // ---- softmax (exp2 domain), defer-max THR=8 ----
    float m0a = fmaxf(fmaxf(s_acc[0][0], s_acc[0][1]), fmaxf(s_acc[0][2], s_acc[0][3]));
    float m1a = fmaxf(fmaxf(s_acc[1][0], s_acc[1][1]), fmaxf(s_acc[1][2], s_acc[1][3]));
    float m2a = fmaxf(fmaxf(s_acc[2][0], s_acc[2][1]), fmaxf(s_acc[2][2], s_acc[2][3]));
    float m3a = fmaxf(fmaxf(s_acc[3][0], s_acc[3][1]), fmaxf(s_acc[3][2], s_acc[3][3]));
    float pm = fmaxf(fmaxf(m0a, m1a), fmaxf(m2a, m3a));
    pm = fmaxf(pm, __shfl_xor(pm, 16, 64));
    pm = fmaxf(pm, __shfl_xor(pm, 32, 64));
    if (!__all(pm - m_run <= 8.0f)) {
      const float mn = fmaxf(m_run, pm);
      const float corr = fast_exp2(m_run - mn);
      m_run = mn;
      l_run *= corr;
#pragma unroll
      for (int g = 0; g < 4; g++)
#pragma unroll
        for (int j = 0; j < 4; j++) o_acc[g][j] *= corr;
    }
    float p[4][4];
#pragma unroll
    for (int g = 0; g < 4; g++)
#pragma unroll
      for (int j = 0; j < 4; j++) {
        p[g][j] = fast_exp2(s_acc[g][j] - m_run);
        l_run += p[g][j];
      }

    // ---- PV via 16x16x16: B-frag = p[kb][0..3] directly (no butterfly) ----
    __builtin_amdgcn_s_setprio(1);
#pragma unroll
    for (int kb = 0; kb < 4; kb++) {
      uint2v pw = {pk2h(p[kb][0], p[kb][1]), pk2h(p[kb][2], p[kb][3])};
      half4 pbh = __builtin_bit_cast(half4, pw);
      const int c = kb * 2 + (lg >> 1);
      const int off = ((c ^ rmask7) * 8 + (lg & 1) * 4);
#pragma unroll
      for (int g = 0; g < 4; g++) {
        half4 va = ld_h4(&smemV[cur][(g * 16 + l15) * 64 + off]);
        o_acc[g] = MFMAH16(va, pbh, o_acc[g]);
      }
    }
    __builtin_amdgcn_s_setprio(0);
  }

  // ---- epilogue: reduce l across the 4 q-column lanes, write partials ----
  l_run += __shfl_xor(l_run, 16, 64);
  l_run += __shfl_xor(l_run, 32, 64);
  const int q = qt * 64 + w * 16 + l15;
  const size_t pidx = ((size_t)(sp * 24 + bh) * NN + q);
#pragma unroll
  for (int g = 0; g < 4; g++) {
    *reinterpret_cast<float4*>(&PartO[pidx * 64 + g * 16 + lg * 4]) =
        make_float4(o_acc[g][0], o_acc[g][1], o_acc[g][2], o_acc[g][3]);
  }
  if (lg == 0) {
    Partml[pidx * 2] = m_run;
    Partml[pidx * 2 + 1] = l_run;
  }
#undef STAGE_K
#undef STAGE_V
}

// ---------------- split-K combine: merge NSP partials -> attnf f16 ----------------
__global__ __launch_bounds__(256) void attn_combine_kernel(
    const float* __restrict__ PartO, const float* __restrict__ Partml,
    ushort* __restrict__ Attnf) {
  const int qt = blockIdx.x;  // 0..31
  const int bh = blockIdx.y;  // 0..23
  const int b = bh / NHEAD, h = bh % NHEAD;
  const int tid = threadIdx.x;
  const int q = qt * 64 + (tid >> 2);
  const int d0 = (tid & 3) * 16;

  size_t idx[NSP];
  float mv[NSP], lv[NSP];
  float m = -INFINITY;
#pragma unroll
  for (int s = 0; s < NSP; s++) {
    idx[s] = ((size_t)(s * 24 + bh) * NN + q);
    mv[s] = Partml[idx[s] * 2];
    lv[s] = Partml[idx[s] * 2 + 1];
    m = fmaxf(m, mv[s]);
  }
  float wsum = 0.f, wgt[NSP];
#pragma unroll
  for (int s = 0; s < NSP; s++) {
    wgt[s] = fast_exp2(mv[s] - m);
    wsum += lv[s] * wgt[s];
  }
  const float inv = 1.0f / wsum;

  ushort hv[16];
#pragma unroll
  for (int d = 0; d < 16; d += 4) {
    float acc[4] = {0.f, 0.f, 0.f, 0.f};
#pragma unroll
    for (int s = 0; s < NSP; s++) {
      float4 a = *reinterpret_cast<const float4*>(&PartO[idx[s] * 64 + d0 + d]);
      acc[0] = fmaf(a.x, wgt[s], acc[0]);
      acc[1] = fmaf(a.y, wgt[s], acc[1]);
      acc[2] = fmaf(a.z, wgt[s], acc[2]);
      acc[3] = fmaf(a.w, wgt[s], acc[3]);
    }
#pragma unroll
    for (int i = 0; i < 4; i++) hv[d + i] = f2h(acc[i] * inv);
  }
  ushort* dst = Attnf + (size_t)(b * NN + q) * CC + h * 64 + d0;
  *reinterpret_cast<uint4*>(dst) = *reinterpret_cast<uint4*>(hv);
  *reinterpret_cast<uint4*>(dst + 8) = *reinterpret_cast<uint4*>(hv + 8);
}

// ---------------- launch ----------------
extern "C" void kernel_launch(void* const* d_in, const int* in_sizes, int n_in,
                              void* d_out, int out_size, void* d_ws, size_t ws_size,
                              hipStream_t stream) {
  const float* x = (const float*)d_in[0];
  const float* Wqkv = (const float*)d_in[1];
  const float* Wout = (const float*)d_in[2];
  const float* cos_t = (const float*)d_in[3];
  const float* sin_t = (const float*)d_in[4];
  const float* cos_h = (const float*)d_in[5];
  const float* sin_h = (const float*)d_in[6];
  const float* cos_w = (const float*)d_in[7];
  const float* sin_w = (const float*)d_in[8];
  const int* t_idx = (const int*)d_in[9];
  const int* h_idx = (const int*)d_in[10];
  const int* w_idx = (const int*)d_in[11];
  float* out = (float*)d_out;

  // region0: aliased by qkvh (f16 4096x2304, live gemm->rope) and
  // PartO (NSP*24*2048*64 f32 = 6.29M floats, live attn->combine). Disjoint.
  const size_t R0 = (size_t)4096 * 2304;  // floats
  float* ws = (float*)d_ws;
  ushort* qkvh = (ushort*)ws;
  float* PartO = ws;
  ushort* us = (ushort*)(ws + R0);
  const size_t HS = (size_t)24 * 2048 * 64;  // 3.14M
  ushort* Qf = us;
  ushort* Kf = Qf + HS;
  ushort* Vt = Kf + HS;
  ushort* xf = Vt + HS;                     // 4096*768
  ushort* wqf = xf + (size_t)4096 * 768;    // 2304*768
  ushort* wof = wqf + (size_t)2304 * 768;   // 768*768
  ushort* attnf = wof + (size_t)768 * 768;  // 4096*768
  float* Partml = (float*)(attnf + (size_t)4096 * 768);  // NSP*24*2048*2 fp32

  // merged input conversions (1 dispatch: x rows + Wqkv^T + Wout^T)
  conv_all_kernel<<<dim3(3840), 256, 0, stream>>>(x, xf, Wqkv, wqf, Wout, wof);
  // qkv = x @ Wqkv; q,k -> qkvh f16 row-major, v -> Vt transposed directly
  gemm_f16_kernel<128, true, true><<<dim3(C3 / 96, 4096 / 128), 256, 0, stream>>>(
      xf, wqf, qkvh, Vt, C3);
  // RoPE Q/K (vectorized 8-wide, 768 blocks)
  rope_f16_kernel<<<dim3(BB * NN * 48 / 256), 256, 0, stream>>>(
      qkvh, cos_t, sin_t, cos_h, sin_h, cos_w, sin_w, t_idx, h_idx, w_idx, Qf, Kf);
  // flash attention (f16 MFMA, QBLK=64, split-K=2 -> 1536 blocks = 6/CU)
  attn_mfma_kernel<<<dim3(NN / 64, BB * NHEAD, NSP), 256, 0, stream>>>(Qf, Kf, Vt,
                                                                       PartO, Partml);
  // combine partials -> f16 attnf
  attn_combine_kernel<<<dim3(NN / 64, BB * NHEAD), 256, 0, stream>>>(PartO, Partml,
                                                                     attnf);
  // out = attn @ Wout  (f16 MFMA, fp32 output)
  gemm_f16_kernel<64, false, false><<<dim3(CC / 96, 4096 / 64), 256, 0, stream>>>(
      attnf, wof, out, nullptr, CC);
}

// Round 24
// 108.433 us; speedup vs baseline: 1.0648x; 1.0137x over previous
//
#include <hip/hip_runtime.h>
#include <hip/hip_bf16.h>
#include <math.h>

// Problem constants
#define BB 2
#define NN 2048
#define CC 768
#define NHEAD 12
#define HD 64
#define C3 2304
#define NSP 2  // split-K factor

typedef __attribute__((ext_vector_type(8))) _Float16 half8;
typedef __attribute__((ext_vector_type(4))) _Float16 half4;
typedef __attribute__((ext_vector_type(8))) short short8;
typedef __attribute__((ext_vector_type(4))) float f32x4;
typedef __attribute__((ext_vector_type(2))) unsigned uint2v;
#define MFMAH(a, b, c) __builtin_amdgcn_mfma_f32_16x16x32_f16(a, b, c, 0, 0, 0)
#define MFMAH16(a, b, c) __builtin_amdgcn_mfma_f32_16x16x16f16(a, b, c, 0, 0, 0)

__device__ __forceinline__ float fast_exp2(float x) {
  return __builtin_amdgcn_exp2f(x);  // v_exp_f32 (natively 2^x)
}
__device__ __forceinline__ ushort f2h(float x) {
  _Float16 h = (_Float16)x;  // v_cvt_f16_f32, RTN
  return __builtin_bit_cast(ushort, h);
}
__device__ __forceinline__ float h2f(ushort u) {
  return (float)__builtin_bit_cast(_Float16, u);  // v_cvt_f32_f16
}
__device__ __forceinline__ unsigned pk2h(float a, float b) {
  return __builtin_bit_cast(unsigned, __builtin_amdgcn_cvt_pkrtz(a, b));
}
__device__ __forceinline__ void gload_lds16(const void* gsrc, void* lds) {
  __builtin_amdgcn_global_load_lds(
      (const __attribute__((address_space(1))) unsigned int*)gsrc,
      (__attribute__((address_space(3))) unsigned int*)lds, 16, 0, 0);
}
__device__ __forceinline__ half8 ld_h8(const ushort* p) {
  return __builtin_bit_cast(half8, *reinterpret_cast<const short8*>(p));
}
__device__ __forceinline__ half4 ld_h4(const ushort* p) {
  return __builtin_bit_cast(half4, *reinterpret_cast<const uint2v*>(p));
}

// ---------------- merged conversions: x rows + Wqkv^T + Wout^T, one dispatch ----
__global__ __launch_bounds__(256) void conv_all_kernel(
    const float* __restrict__ X, ushort* __restrict__ Xf,
    const float* __restrict__ Wqkv, ushort* __restrict__ Wqf,
    const float* __restrict__ Wout, ushort* __restrict__ Wof) {
  __shared__ float t[32][33];
  const int bid = blockIdx.x;
  if (bid < 1536) {
    int idx = bid * 256 + threadIdx.x;
    const float4 v0 = *reinterpret_cast<const float4*>(&X[(size_t)idx * 8]);
    const float4 v1 = *reinterpret_cast<const float4*>(&X[(size_t)idx * 8 + 4]);
    ushort h[8] = {f2h(v0.x), f2h(v0.y), f2h(v0.z), f2h(v0.w),
                   f2h(v1.x), f2h(v1.y), f2h(v1.z), f2h(v1.w)};
    *reinterpret_cast<uint4*>(&Xf[(size_t)idx * 8]) = *reinterpret_cast<uint4*>(h);
    return;
  }
  const float* W;
  ushort* Wf;
  int N, n0, k0;
  if (bid < 3264) {
    W = Wqkv;
    Wf = Wqf;
    N = C3;
    const int b2 = bid - 1536;
    n0 = (b2 % 72) * 32;
    k0 = (b2 / 72) * 32;
  } else {
    W = Wout;
    Wf = Wof;
    N = CC;
    const int b3 = bid - 3264;
    n0 = (b3 % 24) * 32;
    k0 = (b3 / 24) * 32;
  }
  const int tx = threadIdx.x & 31, ty = threadIdx.x >> 5;  // 32 x 8
#pragma unroll
  for (int r = 0; r < 4; r++) {
    int kk = ty + r * 8;
    t[kk][tx] = W[(size_t)(k0 + kk) * N + n0 + tx];
  }
  __syncthreads();
#pragma unroll
  for (int r = 0; r < 4; r++) {
    int nn = ty + r * 8;
    Wf[(size_t)(n0 + nn) * CC + k0 + tx] = f2h(t[tx][nn]);
  }
}

// ---------------- f16 MFMA GEMM: C = A @ B^T, BK=64, BN=96 ----------------
template <int BM, bool F16OUT, bool VOUT>
__global__ __launch_bounds__(256) void gemm_f16_kernel(const ushort* __restrict__ A,
                                                       const ushort* __restrict__ B,
                                                       void* __restrict__ Cout,
                                                       ushort* __restrict__ Vt,
                                                       int Nn) {
  constexpr int WM = BM / 2;   // 64 or 32
  constexpr int MR = WM / 16;  // 4 or 2
  constexpr int NR = 3;        // 48/16
  __shared__ __align__(16) ushort Asm[BM * 64];
  __shared__ __align__(16) ushort Bsm[96 * 64];
  const int tid = threadIdx.x;
  const int lane = tid & 63, w = tid >> 6;
  const int l15 = lane & 15, lg = lane >> 4;
  const int wr = w >> 1, wc = w & 1;
  const int m0 = blockIdx.y * BM, n0 = blockIdx.x * 96;
  const int srow = lane >> 3, lc = lane & 7;
  const int scp = lc ^ (srow & 7);  // pre-swizzled logical chunk

  f32x4 acc[MR][NR];
#pragma unroll
  for (int m = 0; m < MR; m++)
#pragma unroll
    for (int n = 0; n < NR; n++) acc[m][n] = (f32x4){0.f, 0.f, 0.f, 0.f};

  for (int k0 = 0; k0 < 768; k0 += 64) {
#pragma unroll
    for (int it = 0; it < BM / 32; it++) {
      int r0 = it * 32 + w * 8;
      int row = r0 + srow;
      gload_lds16(A + (size_t)(m0 + row) * CC + k0 + scp * 8, &Asm[r0 * 64]);
    }
#pragma unroll
    for (int it = 0; it < 3; it++) {
      int r0 = it * 32 + w * 8;
      int row = r0 + srow;
      gload_lds16(B + (size_t)(n0 + row) * CC + k0 + scp * 8, &Bsm[r0 * 64]);
    }
    __syncthreads();

    half8 ah[MR][2], bh[NR][2];
#pragma unroll
    for (int m = 0; m < MR; m++) {
      int row = wr * WM + m * 16 + l15;
#pragma unroll
      for (int s = 0; s < 2; s++)
        ah[m][s] = ld_h8(&Asm[row * 64 + ((s * 4 + lg) ^ (row & 7)) * 8]);
    }
#pragma unroll
    for (int n = 0; n < NR; n++) {
      int col = wc * 48 + n * 16 + l15;
#pragma unroll
      for (int s = 0; s < 2; s++)
        bh[n][s] = ld_h8(&Bsm[col * 64 + ((s * 4 + lg) ^ (col & 7)) * 8]);
    }
#pragma unroll
    for (int s = 0; s < 2; s++)
#pragma unroll
      for (int m = 0; m < MR; m++)
#pragma unroll
        for (int n = 0; n < NR; n++)
          acc[m][n] = MFMAH(ah[m][s], bh[n][s], acc[m][n]);
    __syncthreads();
  }

#pragma unroll
  for (int m = 0; m < MR; m++) {
    const int rbase = m0 + wr * WM + m * 16 + lg * 4;  // 4 consecutive tokens
#pragma unroll
    for (int n = 0; n < NR; n++) {
      int col = n0 + wc * 48 + n * 16 + l15;
      if (VOUT && col >= 1536) {
        const int vcol = col - 1536;
        const int b = rbase >> 11, ntok = rbase & 2047;
        const int bh_ = b * NHEAD + (vcol >> 6), d = vcol & 63;
        uint2v pw = {pk2h(acc[m][n][0], acc[m][n][1]),
                     pk2h(acc[m][n][2], acc[m][n][3])};
        *reinterpret_cast<uint2v*>(Vt + ((size_t)bh_ * HD + d) * NN + ntok) = pw;
      } else {
#pragma unroll
        for (int j = 0; j < 4; j++) {
          if constexpr (F16OUT) {
            ((ushort*)Cout)[(size_t)(rbase + j) * Nn + col] = f2h(acc[m][n][j]);
          } else {
            ((float*)Cout)[(size_t)(rbase + j) * Nn + col] = acc[m][n][j];
          }
        }
      }
    }
  }
}

// ---------------- RoPE (Q/K), 8-wide vectorized, pair-symmetric ----------------
__global__ __launch_bounds__(256) void rope_f16_kernel(
    const ushort* __restrict__ qkvh, const float* __restrict__ cos_t,
    const float* __restrict__ sin_t, const float* __restrict__ cos_h,
    const float* __restrict__ sin_h, const float* __restrict__ cos_w,
    const float* __restrict__ sin_w, const int* __restrict__ t_idx,
    const int* __restrict__ h_idx, const int* __restrict__ w_idx,
    ushort* __restrict__ Qf, ushort* __restrict__ Kf) {
  const int gid = blockIdx.x * 256 + threadIdx.x;  // 0..196607
  const int tok = gid / 48, grp = gid - tok * 48;
  const int b = tok >> 11, n = tok & 2047;
  const float QSC = 0.125f * 1.44269504088896f;

  int j0, off;
  const float *cT, *sT;  // offset so cT[j] indexes by ABSOLUTE j
  if (grp < 12) {
    j0 = grp * 8;
    off = 96;
    const int ti = t_idx[n];
    cT = cos_t + ti * 192;
    sT = sin_t + ti * 192;
  } else if (grp < 30) {
    j0 = 192 + (grp - 12) * 8;
    off = 144;
    const int hi = h_idx[n];
    cT = cos_h + hi * 288 - 192;
    sT = sin_h + hi * 288 - 192;
  } else {
    j0 = 480 + (grp - 30) * 8;
    off = 144;
    const int wi = w_idx[n];
    cT = cos_w + wi * 288 - 480;
    sT = sin_w + wi * 288 - 480;
  }

  const ushort* base = qkvh + (size_t)tok * C3;
  ushort qa[8], qb[8], ka[8], kb[8];
  *reinterpret_cast<uint4*>(qa) = *reinterpret_cast<const uint4*>(base + j0);
  *reinterpret_cast<uint4*>(qb) = *reinterpret_cast<const uint4*>(base + j0 + off);
  *reinterpret_cast<uint4*>(ka) = *reinterpret_cast<const uint4*>(base + 768 + j0);
  *reinterpret_cast<uint4*>(kb) = *reinterpret_cast<const uint4*>(base + 768 + j0 + off);
  float ca[8], sa[8], cb[8], sb[8];
  *reinterpret_cast<float4*>(ca) = *reinterpret_cast<const float4*>(cT + j0);
  *reinterpret_cast<float4*>(ca + 4) = *reinterpret_cast<const float4*>(cT + j0 + 4);
  *reinterpret_cast<float4*>(sa) = *reinterpret_cast<const float4*>(sT + j0);
  *reinterpret_cast<float4*>(sa + 4) = *reinterpret_cast<const float4*>(sT + j0 + 4);
  *reinterpret_cast<float4*>(cb) = *reinterpret_cast<const float4*>(cT + j0 + off);
  *reinterpret_cast<float4*>(cb + 4) = *reinterpret_cast<const float4*>(cT + j0 + off + 4);
  *reinterpret_cast<float4*>(sb) = *reinterpret_cast<const float4*>(sT + j0 + off);
  *reinterpret_cast<float4*>(sb + 4) = *reinterpret_cast<const float4*>(sT + j0 + off + 4);

  ushort qoA[8], qoB[8], koA[8], koB[8];
#pragma unroll
  for (int i = 0; i < 8; i++) {
    float qA = h2f(qa[i]), qB = h2f(qb[i]);
    float kA = h2f(ka[i]), kB = h2f(kb[i]);
    qoA[i] = f2h(fmaf(qA, ca[i], -qB * sa[i]) * QSC);
    qoB[i] = f2h(fmaf(qB, cb[i], qA * sb[i]) * QSC);
    koA[i] = f2h(fmaf(kA, ca[i], -kB * sa[i]));
    koB[i] = f2h(fmaf(kB, cb[i], kA * sb[i]));
  }

  const size_t tb = (size_t)(b * NHEAD) * NN * HD + (size_t)n * HD;
  {
    const size_t oA = tb + (size_t)(j0 >> 6) * NN * HD + (j0 & 63);
    const size_t oB = tb + (size_t)((j0 + off) >> 6) * NN * HD + ((j0 + off) & 63);
    *reinterpret_cast<uint4*>(Qf + oA) = *reinterpret_cast<uint4*>(qoA);
    *reinterpret_cast<uint4*>(Qf + oB) = *reinterpret_cast<uint4*>(qoB);
    *reinterpret_cast<uint4*>(Kf + oA) = *reinterpret_cast<uint4*>(koA);
    *reinterpret_cast<uint4*>(Kf + oB) = *reinterpret_cast<uint4*>(koB);
  }
}

// ---------------- f16 MFMA flash attention, QBLK=64, split-K=2, 6 blocks/CU ----
// Epilogue now writes NORMALIZED f16 partials (O_s/l_s bounded by max|v| ->
// f16-safe); combine does the convex recombination. Halves partial traffic.
__global__ __launch_bounds__(256, 6) void attn_mfma_kernel(
    const ushort* __restrict__ Qf, const ushort* __restrict__ Kf,
    const ushort* __restrict__ Vt, ushort* __restrict__ PartH,
    float* __restrict__ Partml) {
  __shared__ __align__(16) ushort smemK[4096];     // 8KB
  __shared__ __align__(16) ushort smemV[2][4096];  // 16KB
  const int tid = threadIdx.x;
  const int lane = tid & 63, w = tid >> 6;
  const int l15 = lane & 15, lg = lane >> 4;
  const int qt = blockIdx.x;  // 0..31 (64 q-rows each)
  const int bh = blockIdx.y;  // 0..23
  const int sp = blockIdx.z;  // 0..1 (k-range split)
  const size_t kbase = (size_t)bh * NN * HD;  // Qf/Kf token-major
  const size_t vbase = (size_t)bh * HD * NN;  // Vt d-major

  half8 qf[2];
  {
    const int r = qt * 64 + w * 16 + l15;
#pragma unroll
    for (int s = 0; s < 2; s++)
      qf[s] = ld_h8(Qf + kbase + (size_t)r * HD + s * 32 + lg * 8);
  }

  const int srow = lane >> 3;        // staging row-within-group 0..7
  const int sc = (lane & 7) ^ srow;  // pre-swizzled logical chunk

#define STAGE_K(kt_)                                                           \
  {                                                                            \
    _Pragma("unroll") for (int it = 0; it < 2; it++) {                         \
      int r0 = it * 32 + w * 8;                                                \
      int r = r0 + srow;                                                       \
      gload_lds16(Kf + kbase + (size_t)((kt_)*64 + r) * 64 + sc * 8,           \
                  &smemK[r0 * 64]);                                            \
    }                                                                          \
  }
#define STAGE_V(kt_, vb_)                                                      \
  {                                                                            \
    _Pragma("unroll") for (int it = 0; it < 2; it++) {                         \
      int r0 = it * 32 + w * 8;                                                \
      int r = r0 + srow;                                                       \
      gload_lds16(Vt + vbase + (size_t)r * NN + (kt_)*64 + sc * 8,             \
                  &smemV[vb_][r0 * 64]);                                       \
    }                                                                          \
  }

  f32x4 o_acc[4];
#pragma unroll
  for (int g = 0; g < 4; g++) o_acc[g] = (f32x4){0.f, 0.f, 0.f, 0.f};
  float m_run = -INFINITY, l_run = 0.f;  // per-lane partials

  const int rmask7 = l15 & 7;
  const int kt0 = sp * (32 / NSP), ktend = kt0 + (32 / NSP);

  STAGE_V(kt0, 0);
  STAGE_K(kt0);

  for (int kt = kt0; kt < ktend; kt++) {
    const int cur = (kt - kt0) & 1;
    __syncthreads();  // barA: K(kt), V(kt,cur) visible; V[cur^1] free of reads
    if (kt + 1 < ktend) STAGE_V(kt + 1, cur ^ 1);  // lands under this tile

    // ---- S^T = K Q^T (f16, 16x16x32) ----
    f32x4 s_acc[4];
#pragma unroll
    for (int g = 0; g < 4; g++) s_acc[g] = (f32x4){0.f, 0.f, 0.f, 0.f};
    __builtin_amdgcn_s_setprio(1);
#pragma unroll
    for (int g = 0; g < 4; g++) {
      const int r = g * 16 + l15;
#pragma unroll
      for (int s = 0; s < 2; s++) {
        half8 ka = ld_h8(&smemK[r * 64 + ((s * 4 + lg) ^ rmask7) * 8]);
        s_acc[g] = MFMAH(ka, qf[s], s_acc[g]);
      }
    }
    __builtin_amdgcn_s_setprio(0);

    __syncthreads();                      // barB: all waves done reading K(kt)
    if (kt + 1 < ktend) STAGE_K(kt + 1);  // lands under softmax+PV

    // ---- softmax (exp2 domain), defer-max THR=8 ----
    float m0a = fmaxf(fmaxf(s_acc[0][0], s_acc[0][1]), fmaxf(s_acc[0][2], s_acc[0][3]));
    float m1a = fmaxf(fmaxf(s_acc[1][0], s_acc[1][1]), fmaxf(s_acc[1][2], s_acc[1][3]));
    float m2a = fmaxf(fmaxf(s_acc[2][0], s_acc[2][1]), fmaxf(s_acc[2][2], s_acc[2][3]));
    float m3a = fmaxf(fmaxf(s_acc[3][0], s_acc[3][1]), fmaxf(s_acc[3][2], s_acc[3][3]));
    float pm = fmaxf(fmaxf(m0a, m1a), fmaxf(m2a, m3a));
    pm = fmaxf(pm, __shfl_xor(pm, 16, 64));
    pm = fmaxf(pm, __shfl_xor(pm, 32, 64));
    if (!__all(pm - m_run <= 8.0f)) {
      const float mn = fmaxf(m_run, pm);
      const float corr = fast_exp2(m_run - mn);
      m_run = mn;
      l_run *= corr;
#pragma unroll
      for (int g = 0; g < 4; g++)
#pragma unroll
        for (int j = 0; j < 4; j++) o_acc[g][j] *= corr;
    }
    float p[4][4];
#pragma unroll
    for (int g = 0; g < 4; g++)
#pragma unroll
      for (int j = 0; j < 4; j++) {
        p[g][j] = fast_exp2(s_acc[g][j] - m_run);
        l_run += p[g][j];
      }

    // ---- PV via 16x16x16: B-frag = p[kb][0..3] directly (no butterfly) ----
    __builtin_amdgcn_s_setprio(1);
#pragma unroll
    for (int kb = 0; kb < 4; kb++) {
      uint2v pw = {pk2h(p[kb][0], p[kb][1]), pk2h(p[kb][2], p[kb][3])};
      half4 pbh = __builtin_bit_cast(half4, pw);
      const int c = kb * 2 + (lg >> 1);
      const int off = ((c ^ rmask7) * 8 + (lg & 1) * 4);
#pragma unroll
      for (int g = 0; g < 4; g++) {
        half4 va = ld_h4(&smemV[cur][(g * 16 + l15) * 64 + off]);
        o_acc[g] = MFMAH16(va, pbh, o_acc[g]);
      }
    }
    __builtin_amdgcn_s_setprio(0);
  }

  // ---- epilogue: reduce l, normalize, write f16 partials ----
  l_run += __shfl_xor(l_run, 16, 64);
  l_run += __shfl_xor(l_run, 32, 64);
  const float inv = 1.0f / l_run;
  const int q = qt * 64 + w * 16 + l15;
  const size_t pidx = ((size_t)(sp * 24 + bh) * NN + q);
#pragma unroll
  for (int g = 0; g < 4; g++) {
    uint2v pw = {pk2h(o_acc[g][0] * inv, o_acc[g][1] * inv),
                 pk2h(o_acc[g][2] * inv, o_acc[g][3] * inv)};
    *reinterpret_cast<uint2v*>(&PartH[pidx * 64 + g * 16 + lg * 4]) = pw;
  }
  if (lg == 0) {
    Partml[pidx * 2] = m_run;
    Partml[pidx * 2 + 1] = l_run;
  }
#undef STAGE_K
#undef STAGE_V
}

// ---------------- split-K combine: convex-merge f16 partials -> attnf f16 ----
__global__ __launch_bounds__(256) void attn_combine_kernel(
    const ushort* __restrict__ PartH, const float* __restrict__ Partml,
    ushort* __restrict__ Attnf) {
  const int qt = blockIdx.x;  // 0..31
  const int bh = blockIdx.y;  // 0..23
  const int b = bh / NHEAD, h = bh % NHEAD;
  const int tid = threadIdx.x;
  const int q = qt * 64 + (tid >> 2);
  const int d0 = (tid & 3) * 16;

  size_t idx[NSP];
  float mv[NSP], lv[NSP];
  float m = -INFINITY;
#pragma unroll
  for (int s = 0; s < NSP; s++) {
    idx[s] = ((size_t)(s * 24 + bh) * NN + q);
    mv[s] = Partml[idx[s] * 2];
    lv[s] = Partml[idx[s] * 2 + 1];
    m = fmaxf(m, mv[s]);
  }
  float wsum = 0.f, wgt[NSP];
#pragma unroll
  for (int s = 0; s < NSP; s++) {
    wgt[s] = lv[s] * fast_exp2(mv[s] - m);
    wsum += wgt[s];
  }
  const float inv = 1.0f / wsum;
#pragma unroll
  for (int s = 0; s < NSP; s++) wgt[s] *= inv;

  ushort hv[16];
#pragma unroll
  for (int d = 0; d < 16; d += 8) {
    float acc[8] = {0.f, 0.f, 0.f, 0.f, 0.f, 0.f, 0.f, 0.f};
#pragma unroll
    for (int s = 0; s < NSP; s++) {
      ushort a[8];
      *reinterpret_cast<uint4*>(a) =
          *reinterpret_cast<const uint4*>(&PartH[idx[s] * 64 + d0 + d]);
#pragma unroll
      for (int i = 0; i < 8; i++) acc[i] = fmaf(h2f(a[i]), wgt[s], acc[i]);
    }
#pragma unroll
    for (int i = 0; i < 8; i++) hv[d + i] = f2h(acc[i]);
  }
  ushort* dst = Attnf + (size_t)(b * NN + q) * CC + h * 64 + d0;
  *reinterpret_cast<uint4*>(dst) = *reinterpret_cast<uint4*>(hv);
  *reinterpret_cast<uint4*>(dst + 8) = *reinterpret_cast<uint4*>(hv + 8);
}

// ---------------- launch ----------------
extern "C" void kernel_launch(void* const* d_in, const int* in_sizes, int n_in,
                              void* d_out, int out_size, void* d_ws, size_t ws_size,
                              hipStream_t stream) {
  const float* x = (const float*)d_in[0];
  const float* Wqkv = (const float*)d_in[1];
  const float* Wout = (const float*)d_in[2];
  const float* cos_t = (const float*)d_in[3];
  const float* sin_t = (const float*)d_in[4];
  const float* cos_h = (const float*)d_in[5];
  const float* sin_h = (const float*)d_in[6];
  const float* cos_w = (const float*)d_in[7];
  const float* sin_w = (const float*)d_in[8];
  const int* t_idx = (const int*)d_in[9];
  const int* h_idx = (const int*)d_in[10];
  const int* w_idx = (const int*)d_in[11];
  float* out = (float*)d_out;

  // region0: aliased by qkvh (f16 4096x2304, live gemm->rope) and
  // PartH (NSP*24*2048*64 f16 = 6.29M ushorts, live attn->combine). Disjoint.
  const size_t R0 = (size_t)4096 * 2304;  // floats
  float* ws = (float*)d_ws;
  ushort* qkvh = (ushort*)ws;
  ushort* PartH = (ushort*)ws;
  ushort* us = (ushort*)(ws + R0);
  const size_t HS = (size_t)24 * 2048 * 64;  // 3.14M
  ushort* Qf = us;
  ushort* Kf = Qf + HS;
  ushort* Vt = Kf + HS;
  ushort* xf = Vt + HS;                     // 4096*768
  ushort* wqf = xf + (size_t)4096 * 768;    // 2304*768
  ushort* wof = wqf + (size_t)2304 * 768;   // 768*768
  ushort* attnf = wof + (size_t)768 * 768;  // 4096*768
  float* Partml = (float*)(attnf + (size_t)4096 * 768);  // NSP*24*2048*2 fp32

  // merged input conversions (1 dispatch)
  conv_all_kernel<<<dim3(3840), 256, 0, stream>>>(x, xf, Wqkv, wqf, Wout, wof);
  // qkv = x @ Wqkv; q,k -> qkvh f16 row-major, v -> Vt transposed directly
  gemm_f16_kernel<128, true, true><<<dim3(C3 / 96, 4096 / 128), 256, 0, stream>>>(
      xf, wqf, qkvh, Vt, C3);
  // RoPE Q/K (vectorized 8-wide, 768 blocks)
  rope_f16_kernel<<<dim3(BB * NN * 48 / 256), 256, 0, stream>>>(
      qkvh, cos_t, sin_t, cos_h, sin_h, cos_w, sin_w, t_idx, h_idx, w_idx, Qf, Kf);
  // flash attention (f16 MFMA, QBLK=64, split-K=2 -> 1536 blocks = 6/CU)
  attn_mfma_kernel<<<dim3(NN / 64, BB * NHEAD, NSP), 256, 0, stream>>>(Qf, Kf, Vt,
                                                                       PartH, Partml);
  // combine f16 partials -> f16 attnf
  attn_combine_kernel<<<dim3(NN / 64, BB * NHEAD), 256, 0, stream>>>(PartH, Partml,
                                                                     attnf);
  // out = attn @ Wout  (f16 MFMA, fp32 output)
  gemm_f16_kernel<64, false, false><<<dim3(CC / 96, 4096 / 64), 256, 0, stream>>>(
      attnf, wof, out, nullptr, CC);
}